// Round 11
// baseline (38.804 us; speedup 1.0000x reference)
//
#include <hip/hip_runtime.h>

typedef unsigned short u16;
typedef unsigned int u32;
typedef _Float16 f16x8 __attribute__((ext_vector_type(8)));
typedef float f32x16 __attribute__((ext_vector_type(16)));

#define B_ 8
#define C_ 64
#define H_ 112
#define W_ 112
#define HW_ 12544
#define F_ 128
#define OH_ 110
#define OW_ 110
#define OWOH 12100
#define NPOS 96800
#define KK_ 576
#define NT_ 384           // output positions per block
#define NWGF 506          // 253 n-blocks x 2 f-halves; one dispatch round, 2 blocks/CU
#define OCTSTRIDE 802816  // B_*W_*H_*8 elems per c-oct plane
#define AELEMS 73728      // F_*KK_ fp16 elems (kT total)
#define AHALF 36864       // 64f x 576k fp16 = 72KB LDS per block

__device__ __forceinline__ void gl_lds16(const void* g, void* l) {
  __builtin_amdgcn_global_load_lds((const __attribute__((address_space(1))) void*)g,
                                   (__attribute__((address_space(3))) void*)l,
                                   16, 0, 0);
}

// ---- fused prep: blocks 0..895 transpose input; blocks 896..931 convert kernel ----
// input: NCHW fp32 -> [c_oct][b][w][h]{8c} fp16
// kernel: [f][KK] fp32 -> A'[ko16][khalf][f][8c] fp16  (32x32x16 A-frag order:
//   lane reads f=lane&31 at khalf=lane>>5 -> 512B contiguous per 32-lane half)
__global__ __launch_bounds__(256) void prep_all(const float* __restrict__ in,
                                                const float* __restrict__ k,
                                                u16* __restrict__ xT,
                                                u16* __restrict__ kT) {
  const int bid = blockIdx.x;
  const int tid = threadIdx.x;
  if (bid >= 896) {  // kernel conversion: 36 blocks x 2048 elems
    const int base = (bid - 896) * 2048;
#pragma unroll
    for (int t = 0; t < 8; ++t) {
      int idx = base + t * 256 + tid;
      int c = idx & 7;
      int f = (idx >> 3) & 127;
      int hf = (idx >> 10) & 1;
      int ko16 = idx >> 11;
      _Float16 h = (_Float16)k[f * KK_ + ko16 * 16 + hf * 8 + c];
      kT[idx] = __builtin_bit_cast(u16, h);
    }
    return;
  }
  __shared__ float tile[8][8][113];  // [c][h][w], w-pad 1
  const int b = bid / 112;
  const int r = bid % 112;
  const int oct = r / 14;
  const int hs = (r % 14) * 8;

  for (int idx = tid; idx < 8 * 8 * 112; idx += 256) {
    int c = idx / 896;
    int rem = idx - c * 896;
    int h = rem / 112;
    int w = rem - h * 112;
    tile[c][h][w] = in[(((size_t)(b * 64 + oct * 8 + c)) * 112 + (hs + h)) * 112 + w];
  }
  __syncthreads();

  for (int idx = tid; idx < 896; idx += 256) {
    int w = idx >> 3;
    int h = idx & 7;
    f16x8 v;
#pragma unroll
    for (int c = 0; c < 8; ++c) v[c] = (_Float16)tile[c][h][w];
    size_t o = ((((size_t)oct * B_ + b) * W_ + w) * H_ + (hs + h)) * 8;
    *(f16x8*)(xT + o) = v;
  }
}

// ---------------- main: 64f x 384n per block, 32x32x16 MFMA, barrier-free K-loop ----------------
// vs r10: mfma_f32_32x32x16_f16 halves MFMA instr count (12/step/wave) at better rate,
// and its C/D layout (col=lane&31 -> n, verified m74/m101) makes every epilogue store
// 32 lanes x 4B = 128B aligned cachelines -> kills the 1.67x write amplification.
// A-frag: row=lane&31, k=(lane>>5)*8+e (direct analog of the proven 16x16 mapping).
// LDS [ko16][khalf][64f][8c] = 72KB; frag reads 512B contiguous per 32-lane half.
__global__ __launch_bounds__(256, 2) void conv_mfma(
    const u16* __restrict__ xT, const u16* __restrict__ kT,
    float* __restrict__ out) {
  __shared__ u16 lds[AHALF];  // 72KB; 2 blocks/CU

  const int tid = threadIdx.x;
  const int wave = tid >> 6;
  const int lane = tid & 63;
  const int l31 = lane & 31;
  const int hi = lane >> 5;

  // bijective XCD swizzle for 506 (q=63, r=2): f-half pairs stay on one XCD.
  const int orig = blockIdx.x;
  const int xcd = orig & 7;
  const int sub = orig >> 3;
  const int wg = (xcd < 2 ? xcd * 64 : 128 + (xcd - 2) * 63) + sub;
  const int nblk = wg >> 1;
  const int fh = wg & 1;  // which 64-filter half
  const int n0 = nblk * NT_ + wave * 96;

  // ---- B addressing: per-lane position offsets, 3 x 32 = 96 n per wave
  int posOff[3];
#pragma unroll
  for (int ni = 0; ni < 3; ++ni) {
    int n = n0 + ni * 32 + l31;
    if (n >= NPOS) n = 0;
    int b = n / OWOH;
    int r = n - b * OWOH;
    int w = r / OH_;
    int h = r - w * OH_;
    posOff[ni] = ((b * W_ + w) * H_ + h) * 8;
  }

  // ---- step-0 B loads issued BEFORE the stage barrier (tap0: oct = t*2 + hi)
  f16x8 b0[6];
#pragma unroll
  for (int ni = 0; ni < 3; ++ni)
#pragma unroll
    for (int t = 0; t < 2; ++t)
      b0[ni * 2 + t] = *(const f16x8*)(xT + (t * 2 + hi) * OCTSTRIDE + posOff[ni]);

  // ---- stage this block's A-half: LDS chunk m (16B units) = q64*64 + f_local,
  // q64 = ko16*2+khalf; src chunk = q64*128 + fh*64 + f_local
#pragma unroll
  for (int it = 0; it < 18; ++it) {
    const int m = it * 256 + tid;
    const int src = ((m >> 6) << 7) + (fh << 6) + (m & 63);
    gl_lds16(kT + src * 8, (char*)lds + m * 16);
  }
  __syncthreads();  // the ONLY barrier

  f32x16 acc[2][3] = {};

#pragma unroll
  for (int s = 0; s < 18; ++s) {
    const int tap = s >> 1;
    const int half = s & 1;
    const int i = tap / 3;      // W offset
    const int j = tap - i * 3;  // H offset
    const int sShift = (i * H_ + j) * 8;

    // B: 6 per-lane 16B loads from L2; 32 consecutive n per half -> 512B contiguous
    f16x8 bh[6];
    if (s == 0) {
#pragma unroll
      for (int q = 0; q < 6; ++q) bh[q] = b0[q];
    } else {
#pragma unroll
      for (int ni = 0; ni < 3; ++ni)
#pragma unroll
        for (int t = 0; t < 2; ++t)
          bh[ni * 2 + t] = *(const f16x8*)(xT + (half * 4 + t * 2 + hi) * OCTSTRIDE +
                                           posOff[ni] + sShift);
    }

    // A: 4 ds_read_b128 (mi x t), 512B contiguous per 32-lane half: conflict-free
    f16x8 ah[4];
#pragma unroll
    for (int t = 0; t < 2; ++t)
#pragma unroll
      for (int mi = 0; mi < 2; ++mi)
        ah[t * 2 + mi] = *(const f16x8*)&lds[((((s * 2 + t) * 2 + hi) << 6) + mi * 32 + l31) * 8];

#pragma unroll
    for (int t = 0; t < 2; ++t)
#pragma unroll
      for (int mi = 0; mi < 2; ++mi)
#pragma unroll
        for (int ni = 0; ni < 3; ++ni)
          acc[mi][ni] = __builtin_amdgcn_mfma_f32_32x32x16_f16(ah[t * 2 + mi], bh[ni * 2 + t],
                                                               acc[mi][ni], 0, 0, 0);
  }

  // epilogue: col = lane&31 -> n; row = (reg&3) + 8*(reg>>2) + 4*hi -> f_local
#pragma unroll
  for (int ni = 0; ni < 3; ++ni) {
    int n = n0 + ni * 32 + l31;
    if (n >= NPOS) continue;
    int b = n / OWOH;
    int r = n - b * OWOH;
    int w = r / OH_;
    int h = r - w * OH_;
    float* op = out + ((size_t)(b * F_) * OW_ + w) * OH_ + h;
#pragma unroll
    for (int mi = 0; mi < 2; ++mi) {
      const int fbase = fh * 64 + mi * 32 + 4 * hi;
#pragma unroll
      for (int reg = 0; reg < 16; ++reg) {
        int f = fbase + (reg & 3) + 8 * (reg >> 2);
        op[(size_t)f * OWOH] = acc[mi][ni][reg];
      }
    }
  }
}

// ---------------- correctness fallback (ws too small) ----------------
__global__ void naive_conv(const float* __restrict__ in, const float* __restrict__ ker,
                           float* __restrict__ out) {
  int idx = blockIdx.x * 256 + threadIdx.x;
  const int total = B_ * F_ * OW_ * OH_;
  if (idx >= total) return;
  int h = idx % OH_;
  int w = (idx / OH_) % OW_;
  int f = (idx / (OW_ * OH_)) % F_;
  int b = idx / (F_ * OW_ * OH_);
  float s = 0.f;
  for (int tap = 0; tap < 9; ++tap) {
    int i = tap / 3, j = tap % 3;
    const float* ip = in + ((size_t)b * C_ * H_ + (h + j)) * W_ + (w + i);
    const float* kp = ker + (size_t)f * KK_ + tap * C_;
    for (int c = 0; c < C_; ++c) s += ip[(size_t)c * HW_] * kp[c];
  }
  out[idx] = s;
}

extern "C" void kernel_launch(void* const* d_in, const int* in_sizes, int n_in,
                              void* d_out, int out_size, void* d_ws, size_t ws_size,
                              hipStream_t stream) {
  const float* in = (const float*)d_in[0];
  const float* ker = (const float*)d_in[1];
  float* out = (float*)d_out;

  const size_t xElems = (size_t)B_ * H_ * W_ * C_;  // 6,422,528
  const size_t need = (xElems + AELEMS) * 2;        // ~13 MB fp16

  if (ws_size < need) {
    int total = B_ * F_ * OW_ * OH_;
    naive_conv<<<(total + 255) / 256, 256, 0, stream>>>(in, ker, out);
    return;
  }

  u16* xT = (u16*)d_ws;
  u16* kT = xT + xElems;

  prep_all<<<932, 256, 0, stream>>>(in, ker, xT, kT);
  conv_mfma<<<NWGF, 256, 0, stream>>>(xT, kT, out);
}

// Round 12
// 37.331 us; speedup vs baseline: 1.0395x; 1.0395x over previous
//
#include <hip/hip_runtime.h>

typedef unsigned short u16;
typedef unsigned int u32;
typedef _Float16 f16x8 __attribute__((ext_vector_type(8)));
typedef float f32x16 __attribute__((ext_vector_type(16)));

#define B_ 8
#define C_ 64
#define H_ 112
#define W_ 112
#define HW_ 12544
#define F_ 128
#define OH_ 110
#define OW_ 110
#define OWOH 12100
#define NPOS 96800
#define KK_ 576
#define NT_ 384           // output positions per block
#define NWGF 506          // 253 n-blocks x 2 f-halves; one dispatch round, 2 blocks/CU
#define OCTSTRIDE 802816  // B_*W_*H_*8 elems per c-oct plane
#define AELEMS 73728      // F_*KK_ fp16 elems (kT total)
#define AHALF 36864       // 64f x 576k fp16 = 72KB LDS per block

__device__ __forceinline__ void gl_lds16(const void* g, void* l) {
  __builtin_amdgcn_global_load_lds((const __attribute__((address_space(1))) void*)g,
                                   (__attribute__((address_space(3))) void*)l,
                                   16, 0, 0);
}

// ---- fused prep: blocks 0..895 transpose input; blocks 896..931 convert kernel ----
// input: NCHW fp32 -> [c_oct][b][w][h]{8c} fp16
// kernel: [f][KK] fp32 -> A'[ko16][khalf][f][8c] fp16  (32x32x16 A-frag order)
__global__ __launch_bounds__(256) void prep_all(const float* __restrict__ in,
                                                const float* __restrict__ k,
                                                u16* __restrict__ xT,
                                                u16* __restrict__ kT) {
  const int bid = blockIdx.x;
  const int tid = threadIdx.x;
  if (bid >= 896) {  // kernel conversion: 36 blocks x 2048 elems
    const int base = (bid - 896) * 2048;
#pragma unroll
    for (int t = 0; t < 8; ++t) {
      int idx = base + t * 256 + tid;
      int c = idx & 7;
      int f = (idx >> 3) & 127;
      int hf = (idx >> 10) & 1;
      int ko16 = idx >> 11;
      _Float16 h = (_Float16)k[f * KK_ + ko16 * 16 + hf * 8 + c];
      kT[idx] = __builtin_bit_cast(u16, h);
    }
    return;
  }
  __shared__ float tile[8][8][113];  // [c][h][w], w-pad 1
  const int b = bid / 112;
  const int r = bid % 112;
  const int oct = r / 14;
  const int hs = (r % 14) * 8;

  for (int idx = tid; idx < 8 * 8 * 112; idx += 256) {
    int c = idx / 896;
    int rem = idx - c * 896;
    int h = rem / 112;
    int w = rem - h * 112;
    tile[c][h][w] = in[(((size_t)(b * 64 + oct * 8 + c)) * 112 + (hs + h)) * 112 + w];
  }
  __syncthreads();

  for (int idx = tid; idx < 896; idx += 256) {
    int w = idx >> 3;
    int h = idx & 7;
    f16x8 v;
#pragma unroll
    for (int c = 0; c < 8; ++c) v[c] = (_Float16)tile[c][h][w];
    size_t o = ((((size_t)oct * B_ + b) * W_ + w) * H_ + (hs + h)) * 8;
    *(f16x8*)(xT + o) = v;
  }
}

// ---------------- main: 64f x 384n per block, 32x32x16 MFMA, barrier-free K-loop ----------------
// vs r11 (single lever): WAVE n-INTERLEAVE. n = nblk*384 + wave*32 + ni*128 + l31
// instead of wave*96 + ni*32. The 4 waves' step-s B-loads now cover one contiguous
// ~6KB slab -> per-CU per-step footprint ~12KB fits L1 (was ~250KB thrash), and the
// 16B j-tap shifts re-hit L1 lines. Expected L2 B-traffic 218MB -> ~60-80MB.
// Coverage per block unchanged (bijective relabel); epilogue/guard formulas identical.
__global__ __launch_bounds__(256, 2) void conv_mfma(
    const u16* __restrict__ xT, const u16* __restrict__ kT,
    float* __restrict__ out) {
  __shared__ u16 lds[AHALF];  // 72KB; 2 blocks/CU

  const int tid = threadIdx.x;
  const int wave = tid >> 6;
  const int lane = tid & 63;
  const int l31 = lane & 31;
  const int hi = lane >> 5;

  // bijective XCD swizzle for 506 (q=63, r=2): f-half pairs stay on one XCD.
  const int orig = blockIdx.x;
  const int xcd = orig & 7;
  const int sub = orig >> 3;
  const int wg = (xcd < 2 ? xcd * 64 : 128 + (xcd - 2) * 63) + sub;
  const int nblk = wg >> 1;
  const int fh = wg & 1;  // which 64-filter half
  const int n0 = nblk * NT_ + wave * 32;  // interleaved wave slices (32-granular)

  // ---- B addressing: per-lane position offsets, 3 x 32 = 96 n per wave (stride 128)
  int posOff[3];
#pragma unroll
  for (int ni = 0; ni < 3; ++ni) {
    int n = n0 + ni * 128 + l31;
    if (n >= NPOS) n = 0;
    int b = n / OWOH;
    int r = n - b * OWOH;
    int w = r / OH_;
    int h = r - w * OH_;
    posOff[ni] = ((b * W_ + w) * H_ + h) * 8;
  }

  // ---- step-0 B loads issued BEFORE the stage barrier (tap0: oct = t*2 + hi)
  f16x8 b0[6];
#pragma unroll
  for (int ni = 0; ni < 3; ++ni)
#pragma unroll
    for (int t = 0; t < 2; ++t)
      b0[ni * 2 + t] = *(const f16x8*)(xT + (t * 2 + hi) * OCTSTRIDE + posOff[ni]);

  // ---- stage this block's A-half: LDS chunk m (16B units) = q64*64 + f_local,
  // q64 = ko16*2+khalf; src chunk = q64*128 + fh*64 + f_local
#pragma unroll
  for (int it = 0; it < 18; ++it) {
    const int m = it * 256 + tid;
    const int src = ((m >> 6) << 7) + (fh << 6) + (m & 63);
    gl_lds16(kT + src * 8, (char*)lds + m * 16);
  }
  __syncthreads();  // the ONLY barrier

  f32x16 acc[2][3] = {};

#pragma unroll
  for (int s = 0; s < 18; ++s) {
    const int tap = s >> 1;
    const int half = s & 1;
    const int i = tap / 3;      // W offset
    const int j = tap - i * 3;  // H offset
    const int sShift = (i * H_ + j) * 8;

    // B: 6 per-lane 16B loads; the 4 waves' slabs are contiguous -> L1-resident reuse
    f16x8 bh[6];
    if (s == 0) {
#pragma unroll
      for (int q = 0; q < 6; ++q) bh[q] = b0[q];
    } else {
#pragma unroll
      for (int ni = 0; ni < 3; ++ni)
#pragma unroll
        for (int t = 0; t < 2; ++t)
          bh[ni * 2 + t] = *(const f16x8*)(xT + (half * 4 + t * 2 + hi) * OCTSTRIDE +
                                           posOff[ni] + sShift);
    }

    // A: 4 ds_read_b128 (mi x t), 512B contiguous per 32-lane half: conflict-free
    f16x8 ah[4];
#pragma unroll
    for (int t = 0; t < 2; ++t)
#pragma unroll
      for (int mi = 0; mi < 2; ++mi)
        ah[t * 2 + mi] = *(const f16x8*)&lds[((((s * 2 + t) * 2 + hi) << 6) + mi * 32 + l31) * 8];

#pragma unroll
    for (int t = 0; t < 2; ++t)
#pragma unroll
      for (int mi = 0; mi < 2; ++mi)
#pragma unroll
        for (int ni = 0; ni < 3; ++ni)
          acc[mi][ni] = __builtin_amdgcn_mfma_f32_32x32x16_f16(ah[t * 2 + mi], bh[ni * 2 + t],
                                                               acc[mi][ni], 0, 0, 0);
  }

  // epilogue: col = lane&31 -> n; row = (reg&3) + 8*(reg>>2) + 4*hi -> f_local
#pragma unroll
  for (int ni = 0; ni < 3; ++ni) {
    int n = n0 + ni * 128 + l31;
    if (n >= NPOS) continue;
    int b = n / OWOH;
    int r = n - b * OWOH;
    int w = r / OH_;
    int h = r - w * OH_;
    float* op = out + ((size_t)(b * F_) * OW_ + w) * OH_ + h;
#pragma unroll
    for (int mi = 0; mi < 2; ++mi) {
      const int fbase = fh * 64 + mi * 32 + 4 * hi;
#pragma unroll
      for (int reg = 0; reg < 16; ++reg) {
        int f = fbase + (reg & 3) + 8 * (reg >> 2);
        op[(size_t)f * OWOH] = acc[mi][ni][reg];
      }
    }
  }
}

// ---------------- correctness fallback (ws too small) ----------------
__global__ void naive_conv(const float* __restrict__ in, const float* __restrict__ ker,
                           float* __restrict__ out) {
  int idx = blockIdx.x * 256 + threadIdx.x;
  const int total = B_ * F_ * OW_ * OH_;
  if (idx >= total) return;
  int h = idx % OH_;
  int w = (idx / OH_) % OW_;
  int f = (idx / (OW_ * OH_)) % F_;
  int b = idx / (F_ * OW_ * OH_);
  float s = 0.f;
  for (int tap = 0; tap < 9; ++tap) {
    int i = tap / 3, j = tap % 3;
    const float* ip = in + ((size_t)b * C_ * H_ + (h + j)) * W_ + (w + i);
    const float* kp = ker + (size_t)f * KK_ + tap * C_;
    for (int c = 0; c < C_; ++c) s += ip[(size_t)c * HW_] * kp[c];
  }
  out[idx] = s;
}

extern "C" void kernel_launch(void* const* d_in, const int* in_sizes, int n_in,
                              void* d_out, int out_size, void* d_ws, size_t ws_size,
                              hipStream_t stream) {
  const float* in = (const float*)d_in[0];
  const float* ker = (const float*)d_in[1];
  float* out = (float*)d_out;

  const size_t xElems = (size_t)B_ * H_ * W_ * C_;  // 6,422,528
  const size_t need = (xElems + AELEMS) * 2;        // ~13 MB fp16

  if (ws_size < need) {
    int total = B_ * F_ * OW_ * OH_;
    naive_conv<<<(total + 255) / 256, 256, 0, stream>>>(in, ker, out);
    return;
  }

  u16* xT = (u16*)d_ws;
  u16* kT = xT + xElems;

  prep_all<<<932, 256, 0, stream>>>(in, ker, xT, kT);
  conv_mfma<<<NWGF, 256, 0, stream>>>(xT, kT, out);
}

// Round 13
// 36.995 us; speedup vs baseline: 1.0489x; 1.0091x over previous
//
#include <hip/hip_runtime.h>

typedef unsigned short u16;
typedef unsigned int u32;
typedef _Float16 f16x8 __attribute__((ext_vector_type(8)));
typedef float f32x16 __attribute__((ext_vector_type(16)));

#define B_ 8
#define C_ 64
#define H_ 112
#define W_ 112
#define HW_ 12544
#define F_ 128
#define OH_ 110
#define OW_ 110
#define OWOH 12100
#define NPOS 96800
#define KK_ 576
#define NT_ 384           // output positions per block
#define NWGF 506          // 253 n-blocks x 2 f-halves; one dispatch round, 2 blocks/CU
#define OCTSTRIDE 802816  // B_*W_*H_*8 elems per c-oct plane
#define AELEMS 73728      // F_*KK_ fp16 elems (kT total)
#define AHALF 36864       // 64f x 576k fp16 = 72KB LDS per block

__device__ __forceinline__ void gl_lds16(const void* g, void* l) {
  __builtin_amdgcn_global_load_lds((const __attribute__((address_space(1))) void*)g,
                                   (__attribute__((address_space(3))) void*)l,
                                   16, 0, 0);
}

// ---- fused prep: blocks 0..895 transpose input; blocks 896..931 convert kernel ----
// input: NCHW fp32 -> [c_oct][b][w][h]{8c} fp16
// kernel: [f][KK] fp32 -> A'[ko16][khalf][f][8c] fp16  (32x32x16 A-frag order)
__global__ __launch_bounds__(256) void prep_all(const float* __restrict__ in,
                                                const float* __restrict__ k,
                                                u16* __restrict__ xT,
                                                u16* __restrict__ kT) {
  const int bid = blockIdx.x;
  const int tid = threadIdx.x;
  if (bid >= 896) {  // kernel conversion: 36 blocks x 2048 elems
    const int base = (bid - 896) * 2048;
#pragma unroll
    for (int t = 0; t < 8; ++t) {
      int idx = base + t * 256 + tid;
      int c = idx & 7;
      int f = (idx >> 3) & 127;
      int hf = (idx >> 10) & 1;
      int ko16 = idx >> 11;
      _Float16 h = (_Float16)k[f * KK_ + ko16 * 16 + hf * 8 + c];
      kT[idx] = __builtin_bit_cast(u16, h);
    }
    return;
  }
  __shared__ float tile[8][8][113];  // [c][h][w], w-pad 1
  const int b = bid / 112;
  const int r = bid % 112;
  const int oct = r / 14;
  const int hs = (r % 14) * 8;

  for (int idx = tid; idx < 8 * 8 * 112; idx += 256) {
    int c = idx / 896;
    int rem = idx - c * 896;
    int h = rem / 112;
    int w = rem - h * 112;
    tile[c][h][w] = in[(((size_t)(b * 64 + oct * 8 + c)) * 112 + (hs + h)) * 112 + w];
  }
  __syncthreads();

  for (int idx = tid; idx < 896; idx += 256) {
    int w = idx >> 3;
    int h = idx & 7;
    f16x8 v;
#pragma unroll
    for (int c = 0; c < 8; ++c) v[c] = (_Float16)tile[c][h][w];
    size_t o = ((((size_t)oct * B_ + b) * W_ + w) * H_ + (hs + h)) * 8;
    *(f16x8*)(xT + o) = v;
  }
}

// ---------------- main: 64f x 384n per block, 32x32x16 MFMA, barrier-free K-loop ----------------
// vs r12 (single lever): EXPLICIT ONE-STEP B PREFETCH. Step s issues step s+1's six
// dwordx4 BEFORE s's ds_reads/MFMAs -> every B load has a full step (~200+ cyc of MFMA
// across 2 waves) in flight instead of being consumed in-step (issue-distance fix).
// Fully unrolled: bnext/bcur are SSA values, no copies. ~+24 VGPR, still 2 waves/SIMD.
__global__ __launch_bounds__(256, 2) void conv_mfma(
    const u16* __restrict__ xT, const u16* __restrict__ kT,
    float* __restrict__ out) {
  __shared__ u16 lds[AHALF];  // 72KB; 2 blocks/CU

  const int tid = threadIdx.x;
  const int wave = tid >> 6;
  const int lane = tid & 63;
  const int l31 = lane & 31;
  const int hi = lane >> 5;

  // bijective XCD swizzle for 506 (q=63, r=2): f-half pairs stay on one XCD.
  const int orig = blockIdx.x;
  const int xcd = orig & 7;
  const int sub = orig >> 3;
  const int wg = (xcd < 2 ? xcd * 64 : 128 + (xcd - 2) * 63) + sub;
  const int nblk = wg >> 1;
  const int fh = wg & 1;  // which 64-filter half
  const int n0 = nblk * NT_ + wave * 32;  // interleaved wave slices (32-granular)

  // ---- B addressing: per-lane position offsets, 3 x 32 = 96 n per wave (stride 128)
  int posOff[3];
#pragma unroll
  for (int ni = 0; ni < 3; ++ni) {
    int n = n0 + ni * 128 + l31;
    if (n >= NPOS) n = 0;
    int b = n / OWOH;
    int r = n - b * OWOH;
    int w = r / OH_;
    int h = r - w * OH_;
    posOff[ni] = ((b * W_ + w) * H_ + h) * 8;
  }

  // ---- step-0 B loads issued BEFORE the stage barrier (tap0: oct = t*2 + hi)
  f16x8 bcur[6];
#pragma unroll
  for (int ni = 0; ni < 3; ++ni)
#pragma unroll
    for (int t = 0; t < 2; ++t)
      bcur[ni * 2 + t] = *(const f16x8*)(xT + (t * 2 + hi) * OCTSTRIDE + posOff[ni]);

  // ---- stage this block's A-half: LDS chunk m (16B units) = q64*64 + f_local,
  // q64 = ko16*2+khalf; src chunk = q64*128 + fh*64 + f_local
#pragma unroll
  for (int it = 0; it < 18; ++it) {
    const int m = it * 256 + tid;
    const int src = ((m >> 6) << 7) + (fh << 6) + (m & 63);
    gl_lds16(kT + src * 8, (char*)lds + m * 16);
  }
  __syncthreads();  // the ONLY barrier

  f32x16 acc[2][3] = {};

#pragma unroll
  for (int s = 0; s < 18; ++s) {
    // ---- prefetch step s+1's B (issued FIRST; consumed next iteration)
    f16x8 bnext[6];
    if (s < 17) {
      const int sn = s + 1;
      const int tapn = sn >> 1;
      const int halfn = sn & 1;
      const int in_ = tapn / 3;
      const int jn = tapn - in_ * 3;
      const int sShiftN = (in_ * H_ + jn) * 8;
#pragma unroll
      for (int ni = 0; ni < 3; ++ni)
#pragma unroll
        for (int t = 0; t < 2; ++t)
          bnext[ni * 2 + t] = *(const f16x8*)(xT + (halfn * 4 + t * 2 + hi) * OCTSTRIDE +
                                              posOff[ni] + sShiftN);
    }

    // ---- A: 4 ds_read_b128 (mi x t), 512B contiguous per 32-lane half: conflict-free
    f16x8 ah[4];
#pragma unroll
    for (int t = 0; t < 2; ++t)
#pragma unroll
      for (int mi = 0; mi < 2; ++mi)
        ah[t * 2 + mi] = *(const f16x8*)&lds[((((s * 2 + t) * 2 + hi) << 6) + mi * 32 + l31) * 8];

    // ---- MFMAs consume bcur (loaded a full step ago)
#pragma unroll
    for (int t = 0; t < 2; ++t)
#pragma unroll
      for (int mi = 0; mi < 2; ++mi)
#pragma unroll
        for (int ni = 0; ni < 3; ++ni)
          acc[mi][ni] = __builtin_amdgcn_mfma_f32_32x32x16_f16(ah[t * 2 + mi], bcur[ni * 2 + t],
                                                               acc[mi][ni], 0, 0, 0);

    if (s < 17) {
#pragma unroll
      for (int q = 0; q < 6; ++q) bcur[q] = bnext[q];
    }
  }

  // epilogue: col = lane&31 -> n; row = (reg&3) + 8*(reg>>2) + 4*hi -> f_local
#pragma unroll
  for (int ni = 0; ni < 3; ++ni) {
    int n = n0 + ni * 128 + l31;
    if (n >= NPOS) continue;
    int b = n / OWOH;
    int r = n - b * OWOH;
    int w = r / OH_;
    int h = r - w * OH_;
    float* op = out + ((size_t)(b * F_) * OW_ + w) * OH_ + h;
#pragma unroll
    for (int mi = 0; mi < 2; ++mi) {
      const int fbase = fh * 64 + mi * 32 + 4 * hi;
#pragma unroll
      for (int reg = 0; reg < 16; ++reg) {
        int f = fbase + (reg & 3) + 8 * (reg >> 2);
        op[(size_t)f * OWOH] = acc[mi][ni][reg];
      }
    }
  }
}

// ---------------- correctness fallback (ws too small) ----------------
__global__ void naive_conv(const float* __restrict__ in, const float* __restrict__ ker,
                           float* __restrict__ out) {
  int idx = blockIdx.x * 256 + threadIdx.x;
  const int total = B_ * F_ * OW_ * OH_;
  if (idx >= total) return;
  int h = idx % OH_;
  int w = (idx / OH_) % OW_;
  int f = (idx / (OW_ * OH_)) % F_;
  int b = idx / (F_ * OW_ * OH_);
  float s = 0.f;
  for (int tap = 0; tap < 9; ++tap) {
    int i = tap / 3, j = tap % 3;
    const float* ip = in + ((size_t)b * C_ * H_ + (h + j)) * W_ + (w + i);
    const float* kp = ker + (size_t)f * KK_ + tap * C_;
    for (int c = 0; c < C_; ++c) s += ip[(size_t)c * HW_] * kp[c];
  }
  out[idx] = s;
}

extern "C" void kernel_launch(void* const* d_in, const int* in_sizes, int n_in,
                              void* d_out, int out_size, void* d_ws, size_t ws_size,
                              hipStream_t stream) {
  const float* in = (const float*)d_in[0];
  const float* ker = (const float*)d_in[1];
  float* out = (float*)d_out;

  const size_t xElems = (size_t)B_ * H_ * W_ * C_;  // 6,422,528
  const size_t need = (xElems + AELEMS) * 2;        // ~13 MB fp16

  if (ws_size < need) {
    int total = B_ * F_ * OW_ * OH_;
    naive_conv<<<(total + 255) / 256, 256, 0, stream>>>(in, ker, out);
    return;
  }

  u16* xT = (u16*)d_ws;
  u16* kT = xT + xElems;

  prep_all<<<932, 256, 0, stream>>>(in, ker, xT, kT);
  conv_mfma<<<NWGF, 256, 0, stream>>>(xT, kT, out);
}